// Round 1
// baseline (321.274 us; speedup 1.0000x reference)
//
#include <hip/hip_runtime.h>
#include <hip/hip_bf16.h>

typedef __attribute__((ext_vector_type(8))) short short8;
typedef __attribute__((ext_vector_type(4))) float f32x4;

using bf16 = __hip_bfloat16;

#define L_SEQ 2048
#define NB 2
#define DM 1024
#define NH 16
#define NKV 4
#define HDIM 64
#define CAPV 50.0f

__device__ __forceinline__ unsigned short f2bs(float f) {
  bf16 h = __float2bfloat16(f);
  return __builtin_bit_cast(unsigned short, h);
}

// ---------------- x -> bf16 ----------------
__global__ void k_cvt_x(const float* __restrict__ x, ushort* __restrict__ xb) {
  int i = (blockIdx.x * blockDim.x + threadIdx.x) * 4;
  float4 v = *reinterpret_cast<const float4*>(x + i);
  ushort4 o = make_ushort4(f2bs(v.x), f2bs(v.y), f2bs(v.z), f2bs(v.w));
  *reinterpret_cast<ushort4*>(xb + i) = o;
}

// ---------------- W[K][N] f32 -> Wt[N][K] bf16 ----------------
__global__ void k_transpose_w(const float* __restrict__ W, bf16* __restrict__ Wt,
                              int K, int Ncols) {
  __shared__ float tile[32][33];
  int bx = blockIdx.x * 32;  // over Ncols
  int by = blockIdx.y * 32;  // over K
  int tx = threadIdx.x, ty = threadIdx.y;
  #pragma unroll
  for (int j = 0; j < 32; j += 8)
    tile[ty + j][tx] = W[(size_t)(by + ty + j) * Ncols + bx + tx];
  __syncthreads();
  #pragma unroll
  for (int j = 0; j < 32; j += 8)
    Wt[(size_t)(bx + ty + j) * K + by + tx] = __float2bfloat16(tile[tx][ty + j]);
}

// ---------------- GEMM: C[M,N] = A[M,K] @ Bt[N,K]^T + bias ----------------
template<int OUT_F32>
__global__ __launch_bounds__(256) void k_gemm(const bf16* __restrict__ A,
                                              const bf16* __restrict__ Bt,
                                              const float* __restrict__ bias,
                                              void* __restrict__ Cout,
                                              int M, int Ncols, int K) {
  __shared__ __align__(16) bf16 As[128][64];
  __shared__ __align__(16) bf16 Bs[128][64];
  const int t = threadIdx.x;
  const int lane = t & 63;
  const int w = t >> 6;
  const int wr = w >> 1, wc = w & 1;
  const int m0 = blockIdx.y * 128, n0 = blockIdx.x * 128;
  const int lr = lane & 15, lg = lane >> 4;

  f32x4 acc[4][4];
  #pragma unroll
  for (int m = 0; m < 4; ++m)
    #pragma unroll
    for (int n = 0; n < 4; ++n)
      acc[m][n] = f32x4{0.f, 0.f, 0.f, 0.f};

  const int srow = t >> 3;        // 0..31
  const int scol = (t & 7) * 8;   // 0,8,..,56

  for (int kt = 0; kt < K; kt += 64) {
    #pragma unroll
    for (int p = 0; p < 4; ++p) {
      const int row = srow + p * 32;
      *reinterpret_cast<short8*>(&As[row][scol]) =
          *reinterpret_cast<const short8*>(&A[(size_t)(m0 + row) * K + kt + scol]);
      *reinterpret_cast<short8*>(&Bs[row][scol]) =
          *reinterpret_cast<const short8*>(&Bt[(size_t)(n0 + row) * K + kt + scol]);
    }
    __syncthreads();
    #pragma unroll
    for (int ks = 0; ks < 2; ++ks) {
      short8 af[4], bfr[4];
      #pragma unroll
      for (int m = 0; m < 4; ++m)
        af[m] = *reinterpret_cast<const short8*>(&As[wr * 64 + m * 16 + lr][ks * 32 + lg * 8]);
      #pragma unroll
      for (int n = 0; n < 4; ++n)
        bfr[n] = *reinterpret_cast<const short8*>(&Bs[wc * 64 + n * 16 + lr][ks * 32 + lg * 8]);
      #pragma unroll
      for (int m = 0; m < 4; ++m)
        #pragma unroll
        for (int n = 0; n < 4; ++n)
          acc[m][n] = __builtin_amdgcn_mfma_f32_16x16x32_bf16(af[m], bfr[n], acc[m][n], 0, 0, 0);
    }
    __syncthreads();
  }

  #pragma unroll
  for (int m = 0; m < 4; ++m) {
    const int row = m0 + wr * 64 + m * 16 + lg * 4;
    #pragma unroll
    for (int n = 0; n < 4; ++n) {
      const int col = n0 + wc * 64 + n * 16 + lr;
      const float bv = bias[col];
      #pragma unroll
      for (int r = 0; r < 4; ++r) {
        const float v = acc[m][n][r] + bv;
        if (OUT_F32)
          reinterpret_cast<float*>(Cout)[(size_t)(row + r) * Ncols + col] = v;
        else
          reinterpret_cast<bf16*>(Cout)[(size_t)(row + r) * Ncols + col] = __float2bfloat16(v);
      }
    }
  }
}

// ---------------- RMSNorm + RoPE + layout (b,h,l,d) ----------------
__global__ __launch_bounds__(256) void k_rmsrope(
    const bf16* __restrict__ qp, const bf16* __restrict__ kp, const bf16* __restrict__ vp,
    const float* __restrict__ qg, const float* __restrict__ kg,
    const float* __restrict__ rc, const float* __restrict__ rs,
    bf16* __restrict__ qb, bf16* __restrict__ kb, bf16* __restrict__ vb) {
  const int slot = blockIdx.x * 4 + (threadIdx.x >> 6);
  const int lane = threadIdx.x & 63;
  const int b = slot / (L_SEQ * 24);
  const int rem = slot % (L_SEQ * 24);
  const int l = rem / 24;
  const int s = rem % 24;

  if (s >= 20) {  // v: pure layout transform
    const int kv = s - 20;
    vb[(((size_t)b * NKV + kv) * L_SEQ + l) * HDIM + lane] =
        vp[((size_t)b * L_SEQ + l) * (NKV * HDIM) + kv * HDIM + lane];
    return;
  }
  const bool isq = (s < 16);
  const int h = isq ? s : s - 16;
  const bf16* src = isq ? qp : kp;
  const int cols = isq ? NH * HDIM : NKV * HDIM;
  float val = __bfloat162float(src[((size_t)b * L_SEQ + l) * cols + h * HDIM + lane]);
  float ss = val * val;
  #pragma unroll
  for (int o = 1; o < 64; o <<= 1) ss += __shfl_xor(ss, o, 64);
  const float inv = rsqrtf(ss * (1.0f / 64.0f) + 1e-6f);
  const float* g = isq ? qg : kg;
  const float tv = val * inv * g[h * HDIM + lane];
  const float partner = __shfl_xor(tv, 32, 64);
  const float rot = (lane < 32) ? -partner : partner;
  const float out = tv * rc[l * HDIM + lane] + rot * rs[l * HDIM + lane];
  bf16* dst = isq ? qb : kb;
  const int heads = isq ? NH : NKV;
  dst[(((size_t)b * heads + h) * L_SEQ + l) * HDIM + lane] = __float2bfloat16(out);
}

// ---------------- Flash attention with softcap ----------------
__global__ __launch_bounds__(256) void k_attn(
    const bf16* __restrict__ qb, const bf16* __restrict__ kb, const bf16* __restrict__ vb,
    bf16* __restrict__ y, const int* __restrict__ causal_flag) {
  __shared__ __align__(16) bf16 Ks[64][64];
  __shared__ __align__(16) bf16 Vts[64][64];
  __shared__ __align__(16) bf16 Ps[4][16][64];

  const int t = threadIdx.x, lane = t & 63, w = t >> 6;
  const int lr = lane & 15, lg = lane >> 4;
  const int bh = blockIdx.y;            // b*NH + h
  const int b = bh >> 4, h = bh & 15;
  const int kvh = h >> 2;               // n_rep = 4
  const int qt = blockIdx.x;
  const int q0 = qt * 64;
  const bool causal = (*causal_flag) != 0;
  const int nkt = causal ? (qt + 1) : (L_SEQ / 64);

  // Q fragments in registers (16 rows per wave)
  const bf16* qrow = qb + (((size_t)bh) * L_SEQ + q0 + w * 16 + lr) * HDIM;
  short8 qf[2];
  qf[0] = *reinterpret_cast<const short8*>(qrow + lg * 8);
  qf[1] = *reinterpret_cast<const short8*>(qrow + 32 + lg * 8);

  f32x4 oacc[4];
  #pragma unroll
  for (int n = 0; n < 4; ++n) oacc[n] = f32x4{0.f, 0.f, 0.f, 0.f};
  float mstat[4], lstat[4];
  #pragma unroll
  for (int r = 0; r < 4; ++r) { mstat[r] = -1e30f; lstat[r] = 0.f; }

  const bf16* kbase = kb + ((size_t)b * NKV + kvh) * L_SEQ * HDIM;
  const bf16* vbase = vb + ((size_t)b * NKV + kvh) * L_SEQ * HDIM;

  const int srow = t & 63, schunk = t >> 6;  // stage: 64 rows x 4 chunks of 16 cols

  for (int kt = 0; kt < nkt; ++kt) {
    const int k0 = kt * 64;
    {
      const bf16* kr = kbase + (size_t)(k0 + srow) * HDIM + schunk * 16;
      *reinterpret_cast<short8*>(&Ks[srow][schunk * 16]) = *reinterpret_cast<const short8*>(kr);
      *reinterpret_cast<short8*>(&Ks[srow][schunk * 16 + 8]) = *reinterpret_cast<const short8*>(kr + 8);
      const bf16* vr = vbase + (size_t)(k0 + srow) * HDIM + schunk * 16;
      short8 v0 = *reinterpret_cast<const short8*>(vr);
      short8 v1 = *reinterpret_cast<const short8*>(vr + 8);
      #pragma unroll
      for (int e = 0; e < 8; ++e) {
        Vts[schunk * 16 + e][srow] = reinterpret_cast<const bf16*>(&v0)[e];
        Vts[schunk * 16 + 8 + e][srow] = reinterpret_cast<const bf16*>(&v1)[e];
      }
    }
    __syncthreads();

    // S = Q @ K^T  (16 q-rows x 64 keys per wave)
    f32x4 sacc[4];
    #pragma unroll
    for (int n = 0; n < 4; ++n) sacc[n] = f32x4{0.f, 0.f, 0.f, 0.f};
    #pragma unroll
    for (int ks = 0; ks < 2; ++ks) {
      #pragma unroll
      for (int n = 0; n < 4; ++n) {
        short8 kf = *reinterpret_cast<const short8*>(&Ks[n * 16 + lr][ks * 32 + lg * 8]);
        sacc[n] = __builtin_amdgcn_mfma_f32_16x16x32_bf16(qf[ks], kf, sacc[n], 0, 0, 0);
      }
    }

    // softcap + mask + online softmax
    float p[4][4];
    float tmax[4];
    #pragma unroll
    for (int r = 0; r < 4; ++r) tmax[r] = -1e30f;
    const int qrow_base = q0 + w * 16 + lg * 4;
    #pragma unroll
    for (int n = 0; n < 4; ++n) {
      const int key = k0 + n * 16 + lr;
      #pragma unroll
      for (int r = 0; r < 4; ++r) {
        float sv = sacc[n][r] * 0.125f;
        sv = CAPV * tanhf(sv * (1.0f / CAPV));
        if (causal && key > qrow_base + r) sv = -1e30f;
        p[n][r] = sv;
        tmax[r] = fmaxf(tmax[r], sv);
      }
    }
    #pragma unroll
    for (int r = 0; r < 4; ++r) {
      #pragma unroll
      for (int o = 1; o < 16; o <<= 1) tmax[r] = fmaxf(tmax[r], __shfl_xor(tmax[r], o, 64));
    }
    #pragma unroll
    for (int r = 0; r < 4; ++r) {
      const float mnew = fmaxf(mstat[r], tmax[r]);
      const float scale = __expf(mstat[r] - mnew);
      float rowsum = 0.f;
      #pragma unroll
      for (int n = 0; n < 4; ++n) {
        const float pv = __expf(p[n][r] - mnew);
        p[n][r] = pv;
        rowsum += pv;
      }
      #pragma unroll
      for (int o = 1; o < 16; o <<= 1) rowsum += __shfl_xor(rowsum, o, 64);
      mstat[r] = mnew;
      lstat[r] = lstat[r] * scale + rowsum;
      #pragma unroll
      for (int n = 0; n < 4; ++n) oacc[n][r] *= scale;
    }

    // P -> LDS (bf16, per-wave region), layout change for PV A-operand
    #pragma unroll
    for (int n = 0; n < 4; ++n)
      #pragma unroll
      for (int r = 0; r < 4; ++r)
        Ps[w][lg * 4 + r][n * 16 + lr] = __float2bfloat16(p[n][r]);
    __syncthreads();

    // O += P @ V
    #pragma unroll
    for (int ks = 0; ks < 2; ++ks) {
      short8 pf = *reinterpret_cast<const short8*>(&Ps[w][lr][ks * 32 + lg * 8]);
      #pragma unroll
      for (int n = 0; n < 4; ++n) {
        short8 vf = *reinterpret_cast<const short8*>(&Vts[n * 16 + lr][ks * 32 + lg * 8]);
        oacc[n] = __builtin_amdgcn_mfma_f32_16x16x32_bf16(pf, vf, oacc[n], 0, 0, 0);
      }
    }
    __syncthreads();
  }

  // epilogue: O /= l, write y (b, l, h*hd) bf16
  #pragma unroll
  for (int r = 0; r < 4; ++r) {
    const int qg_ = q0 + w * 16 + lg * 4 + r;
    const float invl = 1.0f / lstat[r];
    #pragma unroll
    for (int n = 0; n < 4; ++n) {
      y[((size_t)b * L_SEQ + qg_) * DM + h * HDIM + n * 16 + lr] =
          __float2bfloat16(oacc[n][r] * invl);
    }
  }
}

extern "C" void kernel_launch(void* const* d_in, const int* in_sizes, int n_in,
                              void* d_out, int out_size, void* d_ws, size_t ws_size,
                              hipStream_t stream) {
  (void)in_sizes; (void)n_in; (void)out_size; (void)ws_size;
  const float* x  = (const float*)d_in[0];
  const float* Wq = (const float*)d_in[1];
  const float* bq = (const float*)d_in[2];
  const float* Wk = (const float*)d_in[3];
  const float* bk = (const float*)d_in[4];
  const float* Wv = (const float*)d_in[5];
  const float* bv = (const float*)d_in[6];
  const float* Wo = (const float*)d_in[7];
  const float* bo = (const float*)d_in[8];
  const float* qg = (const float*)d_in[9];
  const float* kg = (const float*)d_in[10];
  const float* rc = (const float*)d_in[11];
  const float* rs = (const float*)d_in[12];
  const int* causal = (const int*)d_in[13];
  float* out = (float*)d_out;

  char* ws = (char*)d_ws;
  size_t off = 0;
  auto alloc = [&](size_t bytes) -> char* {
    char* p = ws + off;
    off += (bytes + 255) & ~(size_t)255;
    return p;
  };
  bf16* xb  = (bf16*)alloc((size_t)4096 * 1024 * 2);
  bf16* wqt = (bf16*)alloc((size_t)1024 * 1024 * 2);
  bf16* wkt = (bf16*)alloc((size_t)256 * 1024 * 2);
  bf16* wvt = (bf16*)alloc((size_t)256 * 1024 * 2);
  bf16* wot = (bf16*)alloc((size_t)1024 * 1024 * 2);
  bf16* qp  = (bf16*)alloc((size_t)4096 * 1024 * 2);
  bf16* kp  = (bf16*)alloc((size_t)4096 * 256 * 2);
  bf16* vp  = (bf16*)alloc((size_t)4096 * 256 * 2);
  bf16* qb  = (bf16*)alloc((size_t)NB * NH * L_SEQ * HDIM * 2);
  bf16* kb  = (bf16*)alloc((size_t)NB * NKV * L_SEQ * HDIM * 2);
  bf16* vb  = (bf16*)alloc((size_t)NB * NKV * L_SEQ * HDIM * 2);
  bf16* y   = (bf16*)alloc((size_t)4096 * 1024 * 2);

  k_cvt_x<<<4096, 256, 0, stream>>>(x, (ushort*)xb);
  k_transpose_w<<<dim3(1024 / 32, 1024 / 32), dim3(32, 8), 0, stream>>>(Wq, wqt, 1024, 1024);
  k_transpose_w<<<dim3(256 / 32, 1024 / 32), dim3(32, 8), 0, stream>>>(Wk, wkt, 1024, 256);
  k_transpose_w<<<dim3(256 / 32, 1024 / 32), dim3(32, 8), 0, stream>>>(Wv, wvt, 1024, 256);
  k_transpose_w<<<dim3(1024 / 32, 1024 / 32), dim3(32, 8), 0, stream>>>(Wo, wot, 1024, 1024);

  k_gemm<0><<<dim3(8, 32), 256, 0, stream>>>(xb, wqt, bq, qp, 4096, 1024, 1024);
  k_gemm<0><<<dim3(2, 32), 256, 0, stream>>>(xb, wkt, bk, kp, 4096, 256, 1024);
  k_gemm<0><<<dim3(2, 32), 256, 0, stream>>>(xb, wvt, bv, vp, 4096, 256, 1024);

  k_rmsrope<<<(NB * L_SEQ * 24) / 4, 256, 0, stream>>>(qp, kp, vp, qg, kg, rc, rs, qb, kb, vb);

  k_attn<<<dim3(L_SEQ / 64, NB * NH), 256, 0, stream>>>(qb, kb, vb, y, causal);

  k_gemm<1><<<dim3(8, 32), 256, 0, stream>>>(y, wot, bo, out, 4096, 1024, 1024);
}

// Round 2
// 214.587 us; speedup vs baseline: 1.4972x; 1.4972x over previous
//
#include <hip/hip_runtime.h>
#include <hip/hip_bf16.h>

typedef __attribute__((ext_vector_type(8))) short short8;
typedef __attribute__((ext_vector_type(4))) float f32x4;

using bf16 = __hip_bfloat16;

#define L_SEQ 2048
#define NB 2
#define DM 1024
#define NH 16
#define NKV 4
#define HDIM 64
#define CAPV 50.0f

__device__ __forceinline__ unsigned short f2bs(float f) {
  bf16 h = __float2bfloat16(f);
  return __builtin_bit_cast(unsigned short, h);
}

__device__ __forceinline__ void gload_lds16(const void* g, void* l) {
  __builtin_amdgcn_global_load_lds(
      (const __attribute__((address_space(1))) void*)g,
      (__attribute__((address_space(3))) void*)l, 16, 0, 0);
}

// ---------------- x -> bf16 ----------------
__global__ void k_cvt_x(const float* __restrict__ x, ushort* __restrict__ xb) {
  int i = (blockIdx.x * blockDim.x + threadIdx.x) * 4;
  float4 v = *reinterpret_cast<const float4*>(x + i);
  ushort4 o = make_ushort4(f2bs(v.x), f2bs(v.y), f2bs(v.z), f2bs(v.w));
  *reinterpret_cast<ushort4*>(xb + i) = o;
}

// ---------------- W[K][N] f32 -> Wt[N][K] bf16 ----------------
__global__ void k_transpose_w(const float* __restrict__ W, bf16* __restrict__ Wt,
                              int K, int Ncols) {
  __shared__ float tile[32][33];
  int bx = blockIdx.x * 32;
  int by = blockIdx.y * 32;
  int tx = threadIdx.x, ty = threadIdx.y;
  #pragma unroll
  for (int j = 0; j < 32; j += 8)
    tile[ty + j][tx] = W[(size_t)(by + ty + j) * Ncols + bx + tx];
  __syncthreads();
  #pragma unroll
  for (int j = 0; j < 32; j += 8)
    Wt[(size_t)(bx + ty + j) * K + by + tx] = __float2bfloat16(tile[tx][ty + j]);
}

// ---------------- GEMM: C[M,N] = A[M,K] @ Bt[N,K]^T + bias ----------------
// OUT_MODE: 0 = bf16 row-major, 1 = f32 row-major, 2 = bf16 transposed (Vt[b][col][l])
template<int OUT_MODE>
__global__ __launch_bounds__(256) void k_gemm(const bf16* __restrict__ A,
                                              const bf16* __restrict__ Bt,
                                              const float* __restrict__ bias,
                                              void* __restrict__ Cout,
                                              int M, int Ncols, int K) {
  __shared__ __align__(16) bf16 As[128 * 64];
  __shared__ __align__(16) bf16 Bs[128 * 64];
  const int t = threadIdx.x;
  const int lane = t & 63;
  const int w = t >> 6;
  const int wr = w >> 1, wc = w & 1;
  const int m0 = blockIdx.y * 128, n0 = blockIdx.x * 128;
  const int lr = lane & 15, lg = lane >> 4;

  f32x4 acc[4][4];
  #pragma unroll
  for (int m = 0; m < 4; ++m)
    #pragma unroll
    for (int n = 0; n < 4; ++n)
      acc[m][n] = f32x4{0.f, 0.f, 0.f, 0.f};

  const int srow = lane >> 3;      // 0..7
  const int scol = (lane & 7) * 8;

  for (int kt = 0; kt < K; kt += 64) {
    #pragma unroll
    for (int p = 0; p < 4; ++p) {
      const int rbase = w * 32 + p * 8;   // wave-uniform
      gload_lds16(&A[(size_t)(m0 + rbase + srow) * K + kt + scol], &As[rbase * 64]);
      gload_lds16(&Bt[(size_t)(n0 + rbase + srow) * K + kt + scol], &Bs[rbase * 64]);
    }
    __syncthreads();
    #pragma unroll
    for (int ks = 0; ks < 2; ++ks) {
      short8 af[4], bfr[4];
      #pragma unroll
      for (int m = 0; m < 4; ++m)
        af[m] = *reinterpret_cast<const short8*>(&As[(wr * 64 + m * 16 + lr) * 64 + ks * 32 + lg * 8]);
      #pragma unroll
      for (int n = 0; n < 4; ++n)
        bfr[n] = *reinterpret_cast<const short8*>(&Bs[(wc * 64 + n * 16 + lr) * 64 + ks * 32 + lg * 8]);
      #pragma unroll
      for (int m = 0; m < 4; ++m)
        #pragma unroll
        for (int n = 0; n < 4; ++n)
          acc[m][n] = __builtin_amdgcn_mfma_f32_16x16x32_bf16(af[m], bfr[n], acc[m][n], 0, 0, 0);
    }
    __syncthreads();
  }

  #pragma unroll
  for (int m = 0; m < 4; ++m) {
    const int row = m0 + wr * 64 + m * 16 + lg * 4;
    #pragma unroll
    for (int n = 0; n < 4; ++n) {
      const int col = n0 + wc * 64 + n * 16 + lr;
      const float bv = bias[col];
      if (OUT_MODE == 2) {
        const int bb = row >> 11, l = row & 2047;
        ushort4 o;
        o.x = f2bs(acc[m][n][0] + bv);
        o.y = f2bs(acc[m][n][1] + bv);
        o.z = f2bs(acc[m][n][2] + bv);
        o.w = f2bs(acc[m][n][3] + bv);
        *reinterpret_cast<ushort4*>(
            &reinterpret_cast<bf16*>(Cout)[((size_t)bb * 256 + col) * L_SEQ + l]) = o;
      } else {
        #pragma unroll
        for (int r = 0; r < 4; ++r) {
          const float v = acc[m][n][r] + bv;
          if (OUT_MODE == 1)
            reinterpret_cast<float*>(Cout)[(size_t)(row + r) * Ncols + col] = v;
          else
            reinterpret_cast<bf16*>(Cout)[(size_t)(row + r) * Ncols + col] = __float2bfloat16(v);
        }
      }
    }
  }
}

// ---------------- RMSNorm + RoPE + layout (b,h,l,d) for q,k ----------------
__global__ __launch_bounds__(256) void k_rmsrope(
    const bf16* __restrict__ qp, const bf16* __restrict__ kp,
    const float* __restrict__ qg, const float* __restrict__ kg,
    const float* __restrict__ rc, const float* __restrict__ rs,
    bf16* __restrict__ qb, bf16* __restrict__ kb) {
  const int slot = blockIdx.x * 4 + (threadIdx.x >> 6);
  const int lane = threadIdx.x & 63;
  const int b = slot / (L_SEQ * 20);
  const int rem = slot % (L_SEQ * 20);
  const int l = rem / 20;
  const int s = rem % 20;

  const bool isq = (s < 16);
  const int h = isq ? s : s - 16;
  const bf16* src = isq ? qp : kp;
  const int cols = isq ? NH * HDIM : NKV * HDIM;
  float val = __bfloat162float(src[((size_t)b * L_SEQ + l) * cols + h * HDIM + lane]);
  float ss = val * val;
  #pragma unroll
  for (int o = 1; o < 64; o <<= 1) ss += __shfl_xor(ss, o, 64);
  const float inv = rsqrtf(ss * (1.0f / 64.0f) + 1e-6f);
  const float* g = isq ? qg : kg;
  const float tv = val * inv * g[h * HDIM + lane];
  const float partner = __shfl_xor(tv, 32, 64);
  const float rot = (lane < 32) ? -partner : partner;
  const float out = tv * rc[l * HDIM + lane] + rot * rs[l * HDIM + lane];
  bf16* dst = isq ? qb : kb;
  const int heads = isq ? NH : NKV;
  dst[(((size_t)b * heads + h) * L_SEQ + l) * HDIM + lane] = __float2bfloat16(out);
}

// ---------------- Flash attention with softcap ----------------
// K in LDS (XOR-swizzled granules, double-buffered, staged via global_load_lds
// with pre-swizzled source). V read directly from global Vt[b][kv][d][L].
// Paired q-tiles (qt, 31-qt) per block for causal load balance.
__global__ __launch_bounds__(256) void k_attn(
    const bf16* __restrict__ qb, const bf16* __restrict__ kb,
    const bf16* __restrict__ vt, bf16* __restrict__ y,
    const int* __restrict__ causal_flag) {
  __shared__ __align__(16) bf16 Ks[2][64 * 64];
  __shared__ __align__(16) bf16 Ps[4 * 16 * 64];

  const int t = threadIdx.x, lane = t & 63, w = t >> 6;
  const int lr = lane & 15, lg = lane >> 4;
  const int bh = blockIdx.y;
  const int b = bh >> 4, h = bh & 15;
  const int kvh = h >> 2;
  const bool causal = (*causal_flag) != 0;

  const bf16* kbase = kb + ((size_t)b * NKV + kvh) * L_SEQ * HDIM;
  const bf16* vbase = vt + ((size_t)b * NKV + kvh) * HDIM * L_SEQ;

  for (int seg = 0; seg < 2; ++seg) {
    const int qt = (seg == 0) ? (int)blockIdx.x : 31 - (int)blockIdx.x;
    const int q0 = qt * 64;
    const int nkt = causal ? (qt + 1) : (L_SEQ / 64);

    const bf16* qrow = qb + (((size_t)bh) * L_SEQ + q0 + w * 16 + lr) * HDIM;
    short8 qf[2];
    qf[0] = *reinterpret_cast<const short8*>(qrow + lg * 8);
    qf[1] = *reinterpret_cast<const short8*>(qrow + 32 + lg * 8);

    f32x4 oacc[4];
    #pragma unroll
    for (int n = 0; n < 4; ++n) oacc[n] = f32x4{0.f, 0.f, 0.f, 0.f};
    float mst[4], lst[4];
    #pragma unroll
    for (int r = 0; r < 4; ++r) { mst[r] = -1e30f; lst[r] = 0.f; }

    __syncthreads();  // protect Ks reuse across segments
    // initial stage into buf 0
    {
      const int k0 = 0;
      #pragma unroll
      for (int i = 0; i < 2; ++i) {
        const int Gbase = i * 256 + w * 64;
        const int G = Gbase + lane;
        const int row = G >> 3, pg = G & 7;
        gload_lds16(kbase + (size_t)(k0 + row) * HDIM + ((pg ^ (row & 7)) * 8),
                    &Ks[0][Gbase * 8]);
      }
    }
    int cur = 0;

    for (int kt = 0; kt < nkt; ++kt) {
      __syncthreads();  // buf[cur] ready (vmcnt drained)

      if (kt + 1 < nkt) {  // prefetch next tile into other buffer
        const int k0n = (kt + 1) * 64;
        #pragma unroll
        for (int i = 0; i < 2; ++i) {
          const int Gbase = i * 256 + w * 64;
          const int G = Gbase + lane;
          const int row = G >> 3, pg = G & 7;
          gload_lds16(kbase + (size_t)(k0n + row) * HDIM + ((pg ^ (row & 7)) * 8),
                      &Ks[cur ^ 1][Gbase * 8]);
        }
      }

      // V fragments straight from global (issued early, consumed at PV)
      short8 vf[2][4];
      #pragma unroll
      for (int ks = 0; ks < 2; ++ks)
        #pragma unroll
        for (int n = 0; n < 4; ++n)
          vf[ks][n] = *reinterpret_cast<const short8*>(
              vbase + (size_t)(n * 16 + lr) * L_SEQ + kt * 64 + ks * 32 + lg * 8);

      // S = Q @ K^T
      f32x4 sacc[4];
      #pragma unroll
      for (int n = 0; n < 4; ++n) sacc[n] = f32x4{0.f, 0.f, 0.f, 0.f};
      #pragma unroll
      for (int ks = 0; ks < 2; ++ks) {
        #pragma unroll
        for (int n = 0; n < 4; ++n) {
          const int krow = n * 16 + lr;
          short8 kf = *reinterpret_cast<const short8*>(
              &Ks[cur][krow * 64 + (((ks * 4 + lg) ^ (krow & 7)) * 8)]);
          sacc[n] = __builtin_amdgcn_mfma_f32_16x16x32_bf16(qf[ks], kf, sacc[n], 0, 0, 0);
        }
      }

      // softcap (tanh via exp) + causal mask + online softmax
      float p[4][4];
      float tmax[4];
      #pragma unroll
      for (int r = 0; r < 4; ++r) tmax[r] = -1e30f;
      const int qrow_base = q0 + w * 16 + lg * 4;
      const int k0 = kt * 64;
      #pragma unroll
      for (int n = 0; n < 4; ++n) {
        const int key = k0 + n * 16 + lr;
        #pragma unroll
        for (int r = 0; r < 4; ++r) {
          // sv = sacc*0.125; cap = 50*tanh(sv/50) = 50 - 100/(exp(sv*0.005)+1)... (2z form)
          const float e = __expf(sacc[n][r] * (0.125f * 2.0f / CAPV));
          float sv = CAPV - 2.0f * CAPV * __builtin_amdgcn_rcpf(e + 1.0f);
          if (causal && key > qrow_base + r) sv = -1e30f;
          p[n][r] = sv;
          tmax[r] = fmaxf(tmax[r], sv);
        }
      }
      #pragma unroll
      for (int r = 0; r < 4; ++r) {
        #pragma unroll
        for (int o = 1; o < 16; o <<= 1) tmax[r] = fmaxf(tmax[r], __shfl_xor(tmax[r], o, 64));
      }
      #pragma unroll
      for (int r = 0; r < 4; ++r) {
        const float mnew = fmaxf(mst[r], tmax[r]);
        const float scale = __expf(mst[r] - mnew);
        float rowsum = 0.f;
        #pragma unroll
        for (int n = 0; n < 4; ++n) {
          const float pv = __expf(p[n][r] - mnew);
          p[n][r] = pv;
          rowsum += pv;
        }
        #pragma unroll
        for (int o = 1; o < 16; o <<= 1) rowsum += __shfl_xor(rowsum, o, 64);
        mst[r] = mnew;
        lst[r] = lst[r] * scale + rowsum;
        #pragma unroll
        for (int n = 0; n < 4; ++n) oacc[n][r] *= scale;
      }

      // P -> LDS (per-wave region, swizzled) ; same-wave readback, no barrier
      #pragma unroll
      for (int n = 0; n < 4; ++n) {
        #pragma unroll
        for (int r = 0; r < 4; ++r) {
          const int prow = lg * 4 + r;
          const int key = n * 16 + lr;
          Ps[w * 1024 + prow * 64 + (((key >> 3) ^ (prow & 7)) * 8) + (key & 7)] =
              __float2bfloat16(p[n][r]);
        }
      }
      #pragma unroll
      for (int ks = 0; ks < 2; ++ks) {
        short8 pf = *reinterpret_cast<const short8*>(
            &Ps[w * 1024 + lr * 64 + (((ks * 4 + lg) ^ (lr & 7)) * 8)]);
        #pragma unroll
        for (int n = 0; n < 4; ++n)
          oacc[n] = __builtin_amdgcn_mfma_f32_16x16x32_bf16(pf, vf[ks][n], oacc[n], 0, 0, 0);
      }
      cur ^= 1;
    }

    // epilogue
    #pragma unroll
    for (int r = 0; r < 4; ++r) {
      const int qg_ = q0 + w * 16 + lg * 4 + r;
      const float invl = 1.0f / lst[r];
      #pragma unroll
      for (int n = 0; n < 4; ++n) {
        y[((size_t)b * L_SEQ + qg_) * DM + h * HDIM + n * 16 + lr] =
            __float2bfloat16(oacc[n][r] * invl);
      }
    }
  }
}

extern "C" void kernel_launch(void* const* d_in, const int* in_sizes, int n_in,
                              void* d_out, int out_size, void* d_ws, size_t ws_size,
                              hipStream_t stream) {
  (void)in_sizes; (void)n_in; (void)out_size; (void)ws_size;
  const float* x  = (const float*)d_in[0];
  const float* Wq = (const float*)d_in[1];
  const float* bq = (const float*)d_in[2];
  const float* Wk = (const float*)d_in[3];
  const float* bk = (const float*)d_in[4];
  const float* Wv = (const float*)d_in[5];
  const float* bv = (const float*)d_in[6];
  const float* Wo = (const float*)d_in[7];
  const float* bo = (const float*)d_in[8];
  const float* qg = (const float*)d_in[9];
  const float* kg = (const float*)d_in[10];
  const float* rc = (const float*)d_in[11];
  const float* rs = (const float*)d_in[12];
  const int* causal = (const int*)d_in[13];
  float* out = (float*)d_out;

  char* ws = (char*)d_ws;
  size_t off = 0;
  auto alloc = [&](size_t bytes) -> char* {
    char* p = ws + off;
    off += (bytes + 255) & ~(size_t)255;
    return p;
  };
  bf16* xb  = (bf16*)alloc((size_t)4096 * 1024 * 2);
  bf16* wqt = (bf16*)alloc((size_t)1024 * 1024 * 2);
  bf16* wkt = (bf16*)alloc((size_t)256 * 1024 * 2);
  bf16* wvt = (bf16*)alloc((size_t)256 * 1024 * 2);
  bf16* wot = (bf16*)alloc((size_t)1024 * 1024 * 2);
  bf16* qp  = (bf16*)alloc((size_t)4096 * 1024 * 2);
  bf16* kp  = (bf16*)alloc((size_t)4096 * 256 * 2);
  bf16* vt  = (bf16*)alloc((size_t)NB * NKV * HDIM * L_SEQ * 2);
  bf16* qb  = (bf16*)alloc((size_t)NB * NH * L_SEQ * HDIM * 2);
  bf16* kb  = (bf16*)alloc((size_t)NB * NKV * L_SEQ * HDIM * 2);
  bf16* y   = (bf16*)alloc((size_t)4096 * 1024 * 2);

  k_cvt_x<<<4096, 256, 0, stream>>>(x, (ushort*)xb);
  k_transpose_w<<<dim3(1024 / 32, 1024 / 32), dim3(32, 8), 0, stream>>>(Wq, wqt, 1024, 1024);
  k_transpose_w<<<dim3(256 / 32, 1024 / 32), dim3(32, 8), 0, stream>>>(Wk, wkt, 1024, 256);
  k_transpose_w<<<dim3(256 / 32, 1024 / 32), dim3(32, 8), 0, stream>>>(Wv, wvt, 1024, 256);
  k_transpose_w<<<dim3(1024 / 32, 1024 / 32), dim3(32, 8), 0, stream>>>(Wo, wot, 1024, 1024);

  k_gemm<0><<<dim3(8, 32), 256, 0, stream>>>(xb, wqt, bq, qp, 4096, 1024, 1024);
  k_gemm<0><<<dim3(2, 32), 256, 0, stream>>>(xb, wkt, bk, kp, 4096, 256, 1024);
  k_gemm<2><<<dim3(2, 32), 256, 0, stream>>>(xb, wvt, bv, vt, 4096, 256, 1024);

  k_rmsrope<<<(NB * L_SEQ * 20) / 4, 256, 0, stream>>>(qp, kp, qg, kg, rc, rs, qb, kb);

  k_attn<<<dim3(16, NB * NH), 256, 0, stream>>>(qb, kb, vt, y, causal);

  k_gemm<1><<<dim3(8, 32), 256, 0, stream>>>(y, wot, bo, out, 4096, 1024, 1024);
}

// Round 3
// 166.991 us; speedup vs baseline: 1.9239x; 1.2850x over previous
//
#include <hip/hip_runtime.h>
#include <hip/hip_bf16.h>

typedef __attribute__((ext_vector_type(8))) short short8;
typedef __attribute__((ext_vector_type(4))) float f32x4;

using bf16 = __hip_bfloat16;

#define L_SEQ 2048
#define NB 2
#define DM 1024
#define NH 16
#define NKV 4
#define HDIM 64
#define CAPV 50.0f

#if __has_builtin(__builtin_amdgcn_exp2f)
#define EXP2(x) __builtin_amdgcn_exp2f(x)
#else
#define EXP2(x) exp2f(x)
#endif

__device__ __forceinline__ unsigned short f2bs(float f) {
  bf16 h = __float2bfloat16(f);
  return __builtin_bit_cast(unsigned short, h);
}

__device__ __forceinline__ void gload_lds16(const void* g, void* l) {
  __builtin_amdgcn_global_load_lds(
      (const __attribute__((address_space(1))) void*)g,
      (__attribute__((address_space(3))) void*)l, 16, 0, 0);
}

// ---------------- x -> bf16 ----------------
__global__ void k_cvt_x(const float* __restrict__ x, ushort* __restrict__ xb) {
  int i = (blockIdx.x * blockDim.x + threadIdx.x) * 4;
  float4 v = *reinterpret_cast<const float4*>(x + i);
  ushort4 o = make_ushort4(f2bs(v.x), f2bs(v.y), f2bs(v.z), f2bs(v.w));
  *reinterpret_cast<ushort4*>(xb + i) = o;
}

// ---------------- all W[K][N] f32 -> Wt[N][K] bf16, one launch ----------------
__global__ void k_transpose_all(const float* __restrict__ Wq, const float* __restrict__ Wk,
                                const float* __restrict__ Wv, const float* __restrict__ Wo,
                                bf16* __restrict__ wqt, bf16* __restrict__ wkt,
                                bf16* __restrict__ wvt, bf16* __restrict__ wot) {
  __shared__ float tile[32][33];
  const int z = blockIdx.z;
  const float* W = (z == 0) ? Wq : (z == 1) ? Wk : (z == 2) ? Wv : Wo;
  bf16* Wt = (z == 0) ? wqt : (z == 1) ? wkt : (z == 2) ? wvt : wot;
  const int Ncols = (z == 1 || z == 2) ? 256 : 1024;
  const int bx = blockIdx.x * 32;
  if (bx >= Ncols) return;
  const int by = blockIdx.y * 32;
  const int tx = threadIdx.x, ty = threadIdx.y;
  #pragma unroll
  for (int j = 0; j < 32; j += 8)
    tile[ty + j][tx] = W[(size_t)(by + ty + j) * Ncols + bx + tx];
  __syncthreads();
  #pragma unroll
  for (int j = 0; j < 32; j += 8)
    Wt[(size_t)(bx + ty + j) * 1024 + by + tx] = __float2bfloat16(tile[tx][ty + j]);
}

// ---------------- GEMM: C[M,N] = A[M,K] @ Bt[N,K]^T + bias ----------------
// BM=64, BN=128, BK=64. LDS granule-XOR swizzled (pre-swizzled gload src).
// OUT_MODE: 0 = bf16 row-major, 1 = f32 row-major, 2 = bf16 transposed Vt
template<int OUT_MODE>
__global__ __launch_bounds__(256) void k_gemm(const bf16* __restrict__ A,
                                              const bf16* __restrict__ Bt,
                                              const float* __restrict__ bias,
                                              void* __restrict__ Cout,
                                              int M, int Ncols, int K) {
  __shared__ __align__(16) bf16 As[64 * 64];
  __shared__ __align__(16) bf16 Bs[128 * 64];
  const int t = threadIdx.x;
  const int lane = t & 63;
  const int w = t >> 6;
  const int wr = w >> 1, wc = w & 1;
  const int m0 = blockIdx.y * 64, n0 = blockIdx.x * 128;
  const int lr = lane & 15, lg = lane >> 4;

  f32x4 acc[2][4];
  #pragma unroll
  for (int m = 0; m < 2; ++m)
    #pragma unroll
    for (int n = 0; n < 4; ++n)
      acc[m][n] = f32x4{0.f, 0.f, 0.f, 0.f};

  for (int kt = 0; kt < K; kt += 64) {
    #pragma unroll
    for (int p = 0; p < 2; ++p) {
      const int Gb = p * 256 + w * 64;
      const int G = Gb + lane;
      const int row = G >> 3, gc = G & 7;
      gload_lds16(&A[(size_t)(m0 + row) * K + kt + ((gc ^ (row & 7)) * 8)], &As[Gb * 8]);
    }
    #pragma unroll
    for (int p = 0; p < 4; ++p) {
      const int Gb = p * 256 + w * 64;
      const int G = Gb + lane;
      const int row = G >> 3, gc = G & 7;
      gload_lds16(&Bt[(size_t)(n0 + row) * K + kt + ((gc ^ (row & 7)) * 8)], &Bs[Gb * 8]);
    }
    __syncthreads();
    #pragma unroll
    for (int ks = 0; ks < 2; ++ks) {
      short8 af[2], bfr[4];
      #pragma unroll
      for (int m = 0; m < 2; ++m) {
        const int row = wr * 32 + m * 16 + lr;
        af[m] = *reinterpret_cast<const short8*>(&As[row * 64 + (((ks * 4 + lg) ^ (row & 7)) * 8)]);
      }
      #pragma unroll
      for (int n = 0; n < 4; ++n) {
        const int row = wc * 64 + n * 16 + lr;
        bfr[n] = *reinterpret_cast<const short8*>(&Bs[row * 64 + (((ks * 4 + lg) ^ (row & 7)) * 8)]);
      }
      #pragma unroll
      for (int m = 0; m < 2; ++m)
        #pragma unroll
        for (int n = 0; n < 4; ++n)
          acc[m][n] = __builtin_amdgcn_mfma_f32_16x16x32_bf16(af[m], bfr[n], acc[m][n], 0, 0, 0);
    }
    __syncthreads();
  }

  #pragma unroll
  for (int m = 0; m < 2; ++m) {
    const int row = m0 + wr * 32 + m * 16 + lg * 4;
    #pragma unroll
    for (int n = 0; n < 4; ++n) {
      const int col = n0 + wc * 64 + n * 16 + lr;
      const float bv = bias[col];
      if (OUT_MODE == 2) {
        const int bb = row >> 11, l = row & 2047;
        ushort4 o;
        o.x = f2bs(acc[m][n][0] + bv);
        o.y = f2bs(acc[m][n][1] + bv);
        o.z = f2bs(acc[m][n][2] + bv);
        o.w = f2bs(acc[m][n][3] + bv);
        *reinterpret_cast<ushort4*>(
            &reinterpret_cast<bf16*>(Cout)[((size_t)bb * 256 + col) * L_SEQ + l]) = o;
      } else {
        #pragma unroll
        for (int r = 0; r < 4; ++r) {
          const float v = acc[m][n][r] + bv;
          if (OUT_MODE == 1)
            reinterpret_cast<float*>(Cout)[(size_t)(row + r) * Ncols + col] = v;
          else
            reinterpret_cast<bf16*>(Cout)[(size_t)(row + r) * Ncols + col] = __float2bfloat16(v);
        }
      }
    }
  }
}

// ---------------- RMSNorm + RoPE + layout (b,h,l,d) for q,k ----------------
__global__ __launch_bounds__(256) void k_rmsrope(
    const bf16* __restrict__ qp, const bf16* __restrict__ kp,
    const float* __restrict__ qg, const float* __restrict__ kg,
    const float* __restrict__ rc, const float* __restrict__ rs,
    bf16* __restrict__ qb, bf16* __restrict__ kb) {
  const int slot = blockIdx.x * 4 + (threadIdx.x >> 6);
  const int lane = threadIdx.x & 63;
  const int b = slot / (L_SEQ * 20);
  const int rem = slot % (L_SEQ * 20);
  const int l = rem / 20;
  const int s = rem % 20;

  const bool isq = (s < 16);
  const int h = isq ? s : s - 16;
  const bf16* src = isq ? qp : kp;
  const int cols = isq ? NH * HDIM : NKV * HDIM;
  float val = __bfloat162float(src[((size_t)b * L_SEQ + l) * cols + h * HDIM + lane]);
  float ss = val * val;
  #pragma unroll
  for (int o = 1; o < 64; o <<= 1) ss += __shfl_xor(ss, o, 64);
  const float inv = rsqrtf(ss * (1.0f / 64.0f) + 1e-6f);
  const float* g = isq ? qg : kg;
  const float tv = val * inv * g[h * HDIM + lane];
  const float partner = __shfl_xor(tv, 32, 64);
  const float rot = (lane < 32) ? -partner : partner;
  const float out = tv * rc[l * HDIM + lane] + rot * rs[l * HDIM + lane];
  bf16* dst = isq ? qb : kb;
  const int heads = isq ? NH : NKV;
  dst[(((size_t)b * heads + h) * L_SEQ + l) * HDIM + lane] = __float2bfloat16(out);
}

// ---------------- Flash attention, softcap via poly-tanh, fixed-max softmax ----
__global__ __launch_bounds__(256) void k_attn(
    const bf16* __restrict__ qb, const bf16* __restrict__ kb,
    const bf16* __restrict__ vt, bf16* __restrict__ y,
    const int* __restrict__ causal_flag) {
  __shared__ __align__(16) bf16 Ks[2][64 * 64];
  __shared__ __align__(16) bf16 Ps[4 * 16 * 64];

  const int t = threadIdx.x, lane = t & 63, w = t >> 6;
  const int lr = lane & 15, lg = lane >> 4;
  const int bh = blockIdx.y;
  const int b = bh >> 4, h = bh & 15;
  const int kvh = h >> 2;
  const bool causal = (*causal_flag) != 0;

  const bf16* kbase = kb + ((size_t)b * NKV + kvh) * L_SEQ * HDIM;
  const bf16* vbase = vt + ((size_t)b * NKV + kvh) * HDIM * L_SEQ;

  for (int seg = 0; seg < 2; ++seg) {
    const int qt = (seg == 0) ? (int)blockIdx.x : 31 - (int)blockIdx.x;
    const int q0 = qt * 64;
    const int nkt = causal ? (qt + 1) : (L_SEQ / 64);

    const bf16* qrow = qb + (((size_t)bh) * L_SEQ + q0 + w * 16 + lr) * HDIM;
    short8 qf[2];
    qf[0] = *reinterpret_cast<const short8*>(qrow + lg * 8);
    qf[1] = *reinterpret_cast<const short8*>(qrow + 32 + lg * 8);

    f32x4 oacc[4];
    #pragma unroll
    for (int n = 0; n < 4; ++n) oacc[n] = f32x4{0.f, 0.f, 0.f, 0.f};
    float plt[4];  // per-lane partial softmax denominators
    #pragma unroll
    for (int r = 0; r < 4; ++r) plt[r] = 0.f;

    __syncthreads();  // protect Ks reuse across segments
    {
      #pragma unroll
      for (int i = 0; i < 2; ++i) {
        const int Gbase = i * 256 + w * 64;
        const int G = Gbase + lane;
        const int row = G >> 3, pg = G & 7;
        gload_lds16(kbase + (size_t)row * HDIM + ((pg ^ (row & 7)) * 8), &Ks[0][Gbase * 8]);
      }
    }
    int cur = 0;

    for (int kt = 0; kt < nkt; ++kt) {
      __syncthreads();  // buf[cur] ready

      if (kt + 1 < nkt) {
        const int k0n = (kt + 1) * 64;
        #pragma unroll
        for (int i = 0; i < 2; ++i) {
          const int Gbase = i * 256 + w * 64;
          const int G = Gbase + lane;
          const int row = G >> 3, pg = G & 7;
          gload_lds16(kbase + (size_t)(k0n + row) * HDIM + ((pg ^ (row & 7)) * 8),
                      &Ks[cur ^ 1][Gbase * 8]);
        }
      }

      // V fragments from global (L2-resident), issued early
      short8 vf[2][4];
      #pragma unroll
      for (int ks = 0; ks < 2; ++ks)
        #pragma unroll
        for (int n = 0; n < 4; ++n)
          vf[ks][n] = *reinterpret_cast<const short8*>(
              vbase + (size_t)(n * 16 + lr) * L_SEQ + kt * 64 + ks * 32 + lg * 8);

      // S = Q @ K^T
      f32x4 sacc[4];
      #pragma unroll
      for (int n = 0; n < 4; ++n) sacc[n] = f32x4{0.f, 0.f, 0.f, 0.f};
      #pragma unroll
      for (int ks = 0; ks < 2; ++ks) {
        #pragma unroll
        for (int n = 0; n < 4; ++n) {
          const int krow = n * 16 + lr;
          short8 kf = *reinterpret_cast<const short8*>(
              &Ks[cur][krow * 64 + (((ks * 4 + lg) ^ (krow & 7)) * 8)]);
          sacc[n] = __builtin_amdgcn_mfma_f32_16x16x32_bf16(qf[ks], kf, sacc[n], 0, 0, 0);
        }
      }

      // softcap: 50*tanh(S*0.125/50); |x|<=0.16 so tanh(x)=x(1 - x^2/3 + 2x^4/15)
      // work in base-2 with fixed shift -16 (logits bounded by +-50 => safe)
      const int k0 = kt * 64;
      const int qrow_base = q0 + w * 16 + lg * 4;
      float p[4][4];
      #pragma unroll
      for (int n = 0; n < 4; ++n) {
        #pragma unroll
        for (int r = 0; r < 4; ++r) {
          const float xs = sacc[n][r];
          const float u = xs * xs * 6.25e-6f;
          const float poly = fmaf(u, fmaf(u, 0.13333333f, -0.33333333f), 1.0f);
          p[n][r] = fmaf(xs * 0.18033688f, poly, -16.0f);  // 0.125*log2(e)
        }
      }
      if (causal && (k0 + 63 > q0 + w * 16)) {  // wave-uniform: diagonal tile only
        #pragma unroll
        for (int n = 0; n < 4; ++n) {
          const int key = k0 + n * 16 + lr;
          #pragma unroll
          for (int r = 0; r < 4; ++r)
            if (key > qrow_base + r) p[n][r] = -1e30f;
        }
      }
      // p = exp2(sv2), accumulate per-lane denom, write P to LDS (swizzled)
      #pragma unroll
      for (int n = 0; n < 4; ++n) {
        #pragma unroll
        for (int r = 0; r < 4; ++r) {
          const float pv = EXP2(p[n][r]);
          plt[r] += pv;
          const int prow = lg * 4 + r;
          const int key = n * 16 + lr;
          Ps[w * 1024 + prow * 64 + (((key >> 3) ^ (prow & 7)) * 8) + (key & 7)] =
              __float2bfloat16(pv);
        }
      }

      // O += P @ V
      #pragma unroll
      for (int ks = 0; ks < 2; ++ks) {
        short8 pf = *reinterpret_cast<const short8*>(
            &Ps[w * 1024 + lr * 64 + (((ks * 4 + lg) ^ (lr & 7)) * 8)]);
        #pragma unroll
        for (int n = 0; n < 4; ++n)
          oacc[n] = __builtin_amdgcn_mfma_f32_16x16x32_bf16(pf, vf[ks][n], oacc[n], 0, 0, 0);
      }
      cur ^= 1;
    }

    // epilogue: single denom reduce, then write
    #pragma unroll
    for (int r = 0; r < 4; ++r) {
      float ls = plt[r];
      #pragma unroll
      for (int o = 1; o < 16; o <<= 1) ls += __shfl_xor(ls, o, 64);
      const float invl = __builtin_amdgcn_rcpf(ls);
      const int qg_ = q0 + w * 16 + lg * 4 + r;
      #pragma unroll
      for (int n = 0; n < 4; ++n) {
        y[((size_t)b * L_SEQ + qg_) * DM + h * HDIM + n * 16 + lr] =
            __float2bfloat16(oacc[n][r] * invl);
      }
    }
  }
}

extern "C" void kernel_launch(void* const* d_in, const int* in_sizes, int n_in,
                              void* d_out, int out_size, void* d_ws, size_t ws_size,
                              hipStream_t stream) {
  (void)in_sizes; (void)n_in; (void)out_size; (void)ws_size;
  const float* x  = (const float*)d_in[0];
  const float* Wq = (const float*)d_in[1];
  const float* bq = (const float*)d_in[2];
  const float* Wk = (const float*)d_in[3];
  const float* bk = (const float*)d_in[4];
  const float* Wv = (const float*)d_in[5];
  const float* bv = (const float*)d_in[6];
  const float* Wo = (const float*)d_in[7];
  const float* bo = (const float*)d_in[8];
  const float* qg = (const float*)d_in[9];
  const float* kg = (const float*)d_in[10];
  const float* rc = (const float*)d_in[11];
  const float* rs = (const float*)d_in[12];
  const int* causal = (const int*)d_in[13];
  float* out = (float*)d_out;

  char* ws = (char*)d_ws;
  size_t off = 0;
  auto alloc = [&](size_t bytes) -> char* {
    char* p = ws + off;
    off += (bytes + 255) & ~(size_t)255;
    return p;
  };
  bf16* xb  = (bf16*)alloc((size_t)4096 * 1024 * 2);
  bf16* wqt = (bf16*)alloc((size_t)1024 * 1024 * 2);
  bf16* wkt = (bf16*)alloc((size_t)256 * 1024 * 2);
  bf16* wvt = (bf16*)alloc((size_t)256 * 1024 * 2);
  bf16* wot = (bf16*)alloc((size_t)1024 * 1024 * 2);
  bf16* qp  = (bf16*)alloc((size_t)4096 * 1024 * 2);
  bf16* kp  = (bf16*)alloc((size_t)4096 * 256 * 2);
  bf16* vt  = (bf16*)alloc((size_t)NB * NKV * HDIM * L_SEQ * 2);
  bf16* qb  = (bf16*)alloc((size_t)NB * NH * L_SEQ * HDIM * 2);
  bf16* kb  = (bf16*)alloc((size_t)NB * NKV * L_SEQ * HDIM * 2);
  bf16* y   = (bf16*)alloc((size_t)4096 * 1024 * 2);

  k_cvt_x<<<4096, 256, 0, stream>>>(x, (ushort*)xb);
  k_transpose_all<<<dim3(32, 32, 4), dim3(32, 8), 0, stream>>>(Wq, Wk, Wv, Wo, wqt, wkt, wvt, wot);

  k_gemm<0><<<dim3(8, 64), 256, 0, stream>>>(xb, wqt, bq, qp, 4096, 1024, 1024);
  k_gemm<0><<<dim3(2, 64), 256, 0, stream>>>(xb, wkt, bk, kp, 4096, 256, 1024);
  k_gemm<2><<<dim3(2, 64), 256, 0, stream>>>(xb, wvt, bv, vt, 4096, 256, 1024);

  k_rmsrope<<<(NB * L_SEQ * 20) / 4, 256, 0, stream>>>(qp, kp, qg, kg, rc, rs, qb, kb);

  k_attn<<<dim3(16, NB * NH), 256, 0, stream>>>(qb, kb, vt, y, causal);

  k_gemm<1><<<dim3(8, 64), 256, 0, stream>>>(y, wot, bo, out, 4096, 1024, 1024);
}